// Round 6
// baseline (221.608 us; speedup 1.0000x reference)
//
#include <hip/hip_runtime.h>
#include <hip/hip_bf16.h>

#define BLOCK 1024
#define NREG  21

typedef __attribute__((ext_vector_type(8))) short short8;   // 8 bf16
typedef __attribute__((ext_vector_type(4))) float floatx4;
typedef __attribute__((ext_vector_type(4))) unsigned int uint4v;

// LDS map (bytes), total 136192:
//  R1 [0, 72000):      Q f32[252][68] (68544) -> pool bf16[900][40] (72000) -> c2out bf16[676][36] (48672)
//  R2 [72064, 135568): P f32[2][36][68] (19584) -> V bf16[441][72] (63504)
//  [135568, 135696)    feat f32[32]
//  [135696, 135936)    rowinfo[30], colinfo[30] (u32)
//  [135936, 136104)    rep_row[21], rep_col[21] (int)
#define SMEM_Q     0
#define SMEM_POOL  0
#define SMEM_P     72064
#define SMEM_V     72064
#define SMEM_FEAT  135568
#define SMEM_INFO  135696
#define SMEM_REP   135936
#define SMEM_TOTAL 136192

__device__ __forceinline__ int clamp05(int v) { return v < 0 ? 0 : (v > 5 ? 5 : v); }

// joint band id: # breakpoints <= i over 4 edges (5 breakpoints each at e-4..e)
__device__ __forceinline__ int band_id(int i, int e0, int e1, int e2, int e3) {
    int c = 0;
    #pragma unroll
    for (int k = 0; k < 5; ++k) {
        const int b0 = e0 - k, b1 = e1 - k, b2 = e2 - k, b3 = e3 - k;
        c += (b0 >= 1 && i >= b0);
        c += (b1 >= 1 && i >= b1);
        c += (b2 >= 1 && i >= b2);
        c += (b3 >= 1 && i >= b3);
    }
    return c;
}

// pre-kernel: W2 [32 oc][64 ic][25 tap] f32 -> w2t bf16 [25][2 kc][32 n][32 k]
__global__ __launch_bounds__(256) void w2_transform_kernel(
    const float* __restrict__ W2, __hip_bfloat16* __restrict__ w2t)
{
    const int idx = blockIdx.x * 256 + threadIdx.x;   // 51200 total
    if (idx < 51200) {
        const int k   = idx & 31;
        const int n   = (idx >> 5) & 31;
        const int kc  = (idx >> 10) & 1;
        const int tap = idx >> 11;
        w2t[idx] = __float2bfloat16(W2[n*1600 + (kc*32 + k)*25 + tap]);
    }
}

__global__ __launch_bounds__(BLOCK) void vsgnet_mfma_kernel(
    const float* __restrict__ bboxes,
    const int* __restrict__ obj_pairs,
    const int* __restrict__ fw_p,
    const int* __restrict__ fh_p,
    const float* __restrict__ W1,
    const float* __restrict__ b1,
    const __hip_bfloat16* __restrict__ w2t,
    const float* __restrict__ b2,
    const float* __restrict__ Wl,
    const float* __restrict__ bl,
    float* __restrict__ out)
{
    extern __shared__ __align__(16) char smem[];
    float* Qf = (float*)(smem + SMEM_Q);
    float* Pf = (float*)(smem + SMEM_P);
    float* feat = (float*)(smem + SMEM_FEAT);
    unsigned int* rowinfo = (unsigned int*)(smem + SMEM_INFO);
    unsigned int* colinfo = rowinfo + 30;
    int* rep_row = (int*)(smem + SMEM_REP);
    int* rep_col = rep_row + 21;

    const int tid = threadIdx.x;
    const int t = blockIdx.x;
    const int bidx = t >> 6;

    // --- uniform box coords ---
    const int pa = obj_pairs[2*t];
    const int pb = obj_pairs[2*t + 1];
    const float* Ab = bboxes + (bidx*36 + pa)*4;
    const float* Bb = bboxes + (bidx*36 + pb)*4;
    const float sfx = (float)(64.0 / (double)fw_p[0]);
    const float sfy = (float)(64.0 / (double)fh_p[0]);
    const int x0a = (int)floorf(Ab[0]*sfx);
    const int y0a = (int)floorf(Ab[1]*sfy);
    const int x1a = (int)floorf(Ab[2]*sfx);
    const int y1a = (int)floorf(Ab[3]*sfy);
    const int x0b = (int)floorf(Bb[0]*sfx);
    const int y0b = (int)floorf(Bb[1]*sfy);
    const int x1b = (int)floorf(Bb[2]*sfx);
    const int y1b = (int)floorf(Bb[3]*sfy);

    // --- phase A: rep init + P build (stride 68) ---
    if (tid >= 256 && tid < 298) rep_row[tid - 256] = -1;   // covers rep_row+rep_col
    if (tid < 128) {
        const int c = tid & 63;
        const int box = tid >> 6;
        const float* w = W1 + (c*2 + box)*25;
        float p[6][6];
        #pragma unroll
        for (int r = 0; r < 6; ++r) p[r][0] = 0.f;
        #pragma unroll
        for (int cc = 0; cc < 6; ++cc) p[0][cc] = 0.f;
        #pragma unroll
        for (int r = 1; r < 6; ++r)
            #pragma unroll
            for (int cc = 1; cc < 6; ++cc)
                p[r][cc] = w[(r-1)*5 + (cc-1)] + p[r-1][cc] + p[r][cc-1] - p[r-1][cc-1];
        float* Pd = Pf + (box*36)*68;
        #pragma unroll
        for (int r = 0; r < 6; ++r)
            #pragma unroll
            for (int cc = 0; cc < 6; ++cc)
                Pd[(r*6 + cc)*68 + c] = p[r][cc];
    }
    __syncthreads();

    // --- phase B: band tables ---
    if (tid < 30) {
        rowinfo[tid] = (unsigned)band_id(2*tid, y0a, y1a, y0b, y1b)
                     | ((unsigned)band_id(2*tid + 1, y0a, y1a, y0b, y1b) << 8);
    } else if (tid >= 32 && tid < 62) {
        const int j = tid - 32;
        colinfo[j] = (unsigned)band_id(2*j, x0a, x1a, x0b, x1b)
                   | ((unsigned)band_id(2*j + 1, x0a, x1a, x0b, x1b) << 8);
    } else if (tid >= 64 && tid < 124) {
        const int i = tid - 64;
        rep_row[band_id(i, y0a, y1a, y0b, y1b)] = i;
    } else if (tid >= 128 && tid < 188) {
        const int j = tid - 128;
        rep_col[band_id(j, x0a, x1a, x0b, x1b)] = j;
    }

    const int lane = tid & 63;
    const int wid  = tid >> 6;      // 16 waves, all do MFMA
    const int kg   = lane >> 4;
    const int lr   = lane & 15;

    floatx4 acc[3][2];
    #pragma unroll
    for (int s = 0; s < 3; ++s) {
        acc[s][0] = (floatx4){0.f,0.f,0.f,0.f};
        acc[s][1] = (floatx4){0.f,0.f,0.f,0.f};
    }
    int abase[3];
    #pragma unroll
    for (int s = 0; s < 3; ++s) {
        const int mt = wid + 16*s;
        int m = mt*16 + lr; if (m > 675) m = 675;
        const int pi = m / 26;
        const int pj = m - pi*26;
        abase[s] = SMEM_POOL + ((pi*30 + pj)*40 + kg*8)*2;
    }
    __syncthreads();   // P + tables ready

    // --- phase C: Q-build. Q[k=(box*21+rb)*6+c][64ch], stride 68 f32 ---
    for (int idx = tid; idx < 4032; idx += BLOCK) {
        const int g = idx & 15;          // 4-ch granule
        const int k = idx >> 4;          // 0..251
        const int box = (k >= 126);
        const int kk = k - box*126;
        const int rb = kk / 6;
        const int c  = kk - rb*6;
        const int i = rep_row[rb];
        if (i >= 0) {
            int r0, r1;
            if (!box) { r0 = clamp05(y0a - i); r1 = clamp05(y1a - i); }
            else      { r0 = clamp05(y0b - i); r1 = clamp05(y1b - i); }
            const float* Pb_ = Pf + (box*36)*68 + g*4;
            const floatx4 v1 = *(const floatx4*)(Pb_ + (r1*6 + c)*68);
            const floatx4 v0 = *(const floatx4*)(Pb_ + (r0*6 + c)*68);
            *(floatx4*)(Qf + k*68 + g*4) = v1 - v0;
        }
    }
    __syncthreads();

    // --- phase D: V-build (overwrites P; reads Q only). V bf16 [441][72] ---
    for (int idx = tid; idx < 3528; idx += BLOCK) {
        const int g = idx & 7;           // 8-ch granule
        const int combo = idx >> 3;      // 0..440
        const int rb = combo / NREG;
        const int cb = combo - rb*NREG;
        const int j = rep_col[cb];
        if (j >= 0 && rep_row[rb] >= 0) {
            const int c0a = clamp05(x0a - j), c1a = clamp05(x1a - j);
            const int c0b = clamp05(x0b - j), c1b = clamp05(x1b - j);
            const float* qa = Qf + (rb*6)*68 + g*8;
            const float* qb = Qf + (126 + rb*6)*68 + g*8;
            floatx4 v0 = *(const floatx4*)(qa + c1a*68)     - *(const floatx4*)(qa + c0a*68)
                       + *(const floatx4*)(qb + c1b*68)     - *(const floatx4*)(qb + c0b*68);
            floatx4 v1 = *(const floatx4*)(qa + c1a*68 + 4) - *(const floatx4*)(qa + c0a*68 + 4)
                       + *(const floatx4*)(qb + c1b*68 + 4) - *(const floatx4*)(qb + c0b*68 + 4);
            v0 += *(const floatx4*)(b1 + g*8);
            v1 += *(const floatx4*)(b1 + g*8 + 4);
            short8 o;
            #pragma unroll
            for (int e = 0; e < 4; ++e) o[e]   = (short)__bfloat16_as_ushort(__float2bfloat16(v0[e]));
            #pragma unroll
            for (int e = 0; e < 4; ++e) o[4+e] = (short)__bfloat16_as_ushort(__float2bfloat16(v1[e]));
            *(short8*)(smem + SMEM_V + combo*144 + g*16) = o;
        }
    }
    __syncthreads();   // V ready; Q dead

    // --- per 32-ic chunk: pool-build then MFMA (acc carries across chunks) ---
    for (int kc = 0; kc < 2; ++kc) {
        // pool-build: pool[cell][40-pad] <- max of <=4 V combos (8-ch granules)
        for (int idx = tid; idx < 3600; idx += BLOCK) {
            const int g = idx & 3;
            const int cell = idx >> 2;
            const int pi = cell / 30;
            const int pj = cell - pi*30;
            const unsigned ri = rowinfo[pi], ci = colinfo[pj];
            const int rb0 = ri & 255, rb1 = (ri >> 8) & 255;
            const int cb0 = ci & 255, cb1 = (ci >> 8) & 255;
            const int voff = kc*64 + g*16;
            const uint4v u00 = *(const uint4v*)(smem + SMEM_V + (rb0*NREG + cb0)*144 + voff);
            const uint4v u01 = *(const uint4v*)(smem + SMEM_V + (rb0*NREG + cb1)*144 + voff);
            const uint4v u10 = *(const uint4v*)(smem + SMEM_V + (rb1*NREG + cb0)*144 + voff);
            const uint4v u11 = *(const uint4v*)(smem + SMEM_V + (rb1*NREG + cb1)*144 + voff);
            uint4v o;
            #pragma unroll
            for (int u = 0; u < 4; ++u) {
                const float l0 = __uint_as_float(u00[u] << 16), h0 = __uint_as_float(u00[u] & 0xffff0000u);
                const float l1 = __uint_as_float(u01[u] << 16), h1 = __uint_as_float(u01[u] & 0xffff0000u);
                const float l2 = __uint_as_float(u10[u] << 16), h2 = __uint_as_float(u10[u] & 0xffff0000u);
                const float l3 = __uint_as_float(u11[u] << 16), h3 = __uint_as_float(u11[u] & 0xffff0000u);
                const float ml = fmaxf(fmaxf(l0, l1), fmaxf(l2, l3));
                const float mh = fmaxf(fmaxf(h0, h1), fmaxf(h2, h3));
                o[u] = (__float_as_uint(ml) >> 16) | (__float_as_uint(mh) & 0xffff0000u);
            }
            *(uint4v*)(smem + SMEM_POOL + cell*80 + g*16) = o;
        }
        __syncthreads();   // pool chunk ready

        // MFMA: A from LDS pool, B from global w2t (L1/L2-resident)
        #pragma unroll
        for (int tap = 0; tap < 25; ++tap) {
            const int toffA = ((tap/5)*30 + (tap%5))*80;
            const __hip_bfloat16* wb = w2t + (tap*2 + kc)*1024 + kg*8;
            const short8 bf0 = *(const short8*)(wb + lr*32);
            const short8 bf1 = *(const short8*)(wb + (16 + lr)*32);
            #pragma unroll
            for (int s = 0; s < 3; ++s) {
                if (wid + 16*s < 43) {
                    const short8 af = *(const short8*)(smem + abase[s] + toffA);
                    acc[s][0] = __builtin_amdgcn_mfma_f32_16x16x32_bf16(af, bf0, acc[s][0], 0, 0, 0);
                    acc[s][1] = __builtin_amdgcn_mfma_f32_16x16x32_bf16(af, bf1, acc[s][1], 0, 0, 0);
                }
            }
        }
        __syncthreads();   // drain A-reads before pool overwrite / epilogue
    }

    // --- epilogue: C (col=lane&15, row=(lane>>4)*4+reg) -> c2out[m][36] ---
    __hip_bfloat16* c2out = (__hip_bfloat16*)(smem + SMEM_POOL);
    if (tid < 32) feat[tid] = 0.f;
    {
        const float b2v0 = b2[lr];
        const float b2v1 = b2[16 + lr];
        #pragma unroll
        for (int s = 0; s < 3; ++s) {
            const int mt = wid + 16*s;
            if (mt < 43) {
                #pragma unroll
                for (int r = 0; r < 4; ++r) {
                    const int m = mt*16 + kg*4 + r;
                    if (m < 676) {
                        c2out[m*36 + lr]      = __float2bfloat16(acc[s][0][r] + b2v0);
                        c2out[m*36 + 16 + lr] = __float2bfloat16(acc[s][1][r] + b2v1);
                    }
                }
            }
        }
    }
    __syncthreads();

    // --- pool2 2x2 + mean(13x13) ---
    {
        const int oc  = tid & 31;
        const int grp = tid >> 5;
        float sum = 0.f;
        for (int cell = grp; cell < 169; cell += 32) {
            const int ci = cell / 13;
            const int cj = cell - ci*13;
            const __hip_bfloat16* q = c2out + ((ci*2)*26 + cj*2)*36 + oc;
            const float v0 = __bfloat162float(q[0]);
            const float v1 = __bfloat162float(q[36]);
            const float v2 = __bfloat162float(q[936]);
            const float v3 = __bfloat162float(q[972]);
            sum += fmaxf(fmaxf(v0, v1), fmaxf(v2, v3));
        }
        atomicAdd(&feat[oc], sum * (1.0f/169.0f));
    }
    __syncthreads();

    // --- linear 32 -> 512 + ReLU ---
    if (tid < 512) {
        float s = bl[tid];
        #pragma unroll
        for (int ic = 0; ic < 32; ++ic)
            s = fmaf(feat[ic], Wl[ic*512 + tid], s);
        out[(size_t)t*512 + tid] = fmaxf(s, 0.f);
    }
}

extern "C" void kernel_launch(void* const* d_in, const int* in_sizes, int n_in,
                              void* d_out, int out_size, void* d_ws, size_t ws_size,
                              hipStream_t stream) {
    const float* bboxes    = (const float*)d_in[0];
    const int*   obj_pairs = (const int*)d_in[1];
    const int*   fw        = (const int*)d_in[3];
    const int*   fh        = (const int*)d_in[4];
    const float* W1        = (const float*)d_in[5];
    const float* b1        = (const float*)d_in[6];
    const float* W2        = (const float*)d_in[7];
    const float* b2        = (const float*)d_in[8];
    const float* Wl        = (const float*)d_in[9];
    const float* bl        = (const float*)d_in[10];
    float* out = (float*)d_out;
    __hip_bfloat16* w2t = (__hip_bfloat16*)d_ws;    // 102400 B scratch

    w2_transform_kernel<<<dim3(200), dim3(256), 0, stream>>>(W2, w2t);

    hipFuncSetAttribute((const void*)vsgnet_mfma_kernel,
                        hipFuncAttributeMaxDynamicSharedMemorySize, SMEM_TOTAL);
    vsgnet_mfma_kernel<<<dim3(1024), dim3(BLOCK), SMEM_TOTAL, stream>>>(
        bboxes, obj_pairs, fw, fh, W1, b1, w2t, b2, Wl, bl, out);
}